// Round 13
// baseline (55.308 us; speedup 1.0000x reference)
//
#include <hip/hip_runtime.h>
#include <hip/hip_bf16.h>

// PhraseCompressor: B=4, T=4096, D=2048, P=1024, Lmax=8, c=128
#define DIM   2048
#define NC    256
#define CDIM  128
#define NROWS 16384
#define HALFCZ (16384u * 256u)   // elems per split-K partial

typedef __attribute__((ext_vector_type(8))) short short8;
typedef __attribute__((ext_vector_type(4))) float f32x4;

static __device__ __forceinline__ unsigned short f2bf(float f) {
    union { float f; unsigned u; } v; v.f = f;
    return (unsigned short)((v.u + 0x7fffu + ((v.u >> 16) & 1u)) >> 16);  // RNE
}

static __device__ __forceinline__ short8 cvt8(float4 a, float4 b) {
    union { __hip_bfloat162 h2[4]; short8 s; } u;
    u.h2[0] = __float22bfloat162_rn(float2{a.x, a.y});
    u.h2[1] = __float22bfloat162_rn(float2{a.z, a.w});
    u.h2[2] = __float22bfloat162_rn(float2{b.x, b.y});
    u.h2[3] = __float22bfloat162_rn(float2{b.z, b.w});
    return u.s;
}

static __device__ __forceinline__ float2 ld2bf(const unsigned short* p) {
    unsigned v = *(const unsigned*)p;
    union { unsigned u; float f; } lo, hi;
    lo.u = v << 16;
    hi.u = v & 0xffff0000u;
    return float2{lo.f, hi.f};
}

#define BARRIER() { asm volatile("s_waitcnt lgkmcnt(0)" ::: "memory"); \
                    __builtin_amdgcn_s_barrier(); }

// ---------- Kernel 1 (fused): convert W (blocks 0..255) + mark rows (256..383) --
// Wp[((f*64+s)*64+l)*8+e] = W[f*16+(l&15)][s*32+(l>>4)*8+e]
__global__ __launch_bounds__(256) void convmark(const float* __restrict__ Wkv,
                                                const float* __restrict__ Wz,
                                                unsigned short* __restrict__ Wp,
                                                const int* __restrict__ mask,
                                                const int* __restrict__ idx,
                                                int* __restrict__ flags) {
    int bid = blockIdx.x;
    if (bid < 256) {
        int tid = bid * 256 + threadIdx.x;
        int l = tid & 63;
        int s = (tid >> 6) & 63;
        int f = tid >> 12;
        int n = f * 16 + (l & 15);
        int k = s * 32 + ((l >> 4) << 3);
        const float* src = (n < CDIM) ? (Wkv + (size_t)n * DIM + k)
                                      : (Wz + (size_t)(n - CDIM) * DIM + k);
        float4 f0 = *(const float4*)src;
        float4 f1 = *(const float4*)(src + 4);
        *(short8*)(Wp + (size_t)tid * 8) = cvt8(f0, f1);
    } else {
        int s = (bid - 256) * 256 + threadIdx.x;   // 0..32767 slots
        if (mask[s]) {
            int row = (s >> 13) * 4096 + idx[s];   // b*T + tok
            flags[row] = 1;
        }
    }
}

// ---------- Kernel 2: compact flagged rows -> rowlist/invmap/nref ----------
__global__ __launch_bounds__(1024) void compact(const int* __restrict__ flags,
                                                int* __restrict__ rowlist,
                                                int* __restrict__ invmap,
                                                int* __restrict__ nref) {
    __shared__ int psum[1024];
    const int t = threadIdx.x;
    const int base = t * 16;
    int loc[16];
    int cnt = 0;
    #pragma unroll
    for (int i = 0; i < 16; ++i) { loc[i] = cnt; cnt += (flags[base + i] != 0); }
    psum[t] = cnt;
    __syncthreads();
    for (int off = 1; off < 1024; off <<= 1) {
        int v = (t >= off) ? psum[t - off] : 0;
        __syncthreads();
        psum[t] += v;
        __syncthreads();
    }
    const int total = psum[1023];
    const int start = psum[t] - cnt;   // exclusive prefix
    #pragma unroll
    for (int i = 0; i < 16; ++i)
        if (flags[base + i]) {
            int c = start + loc[i];
            rowlist[c] = base + i;
            invmap[base + i] = c;
        }
    if (t == 0) nref[0] = total;
    __syncthreads();
    for (int c = total + t; c < NROWS; c += 1024) rowlist[c] = 0;  // pad
}

// ---------- Kernel 3: CZp[ks][compact][256] = h[rowlist] @ W^T ----------
// Exact r11 structure (best known): BM=64, BN=256, split-K=2, 512 thr = 8 waves,
// wave w: 64 rows x cols w*32..+31 -> acc[4][2]. Grid 384 (<=12288 compact rows),
// early-exit when m0 >= nref. A rows fetched indirectly via rowlist.
__global__ __launch_bounds__(512, 4) void gemm_hw(
    const float* __restrict__ H,
    const unsigned short* __restrict__ Wp,
    const int* __restrict__ rowlist,
    const int* __restrict__ nref,
    unsigned short* __restrict__ CZp)
{
    __shared__ unsigned char As[2 * 64 * 128];

    const int bid    = blockIdx.x;
    const int kslice = bid & 1;
    const int m0     = (bid >> 1) * 64;
    if (m0 >= nref[0]) return;          // tile fully padding -> skip

    const int tid    = threadIdx.x;
    const int lane   = tid & 63;
    const int wave   = tid >> 6;        // 0..7
    const int wn     = wave * 32;

    unsigned short* CZout = CZp + (size_t)kslice * HALFCZ;

    // A staging: thread -> 8 consecutive floats of its (indirect) row
    const int srow = tid >> 3;           // 0..63
    const int scol = (tid & 7) * 8;      // 0..56
    const int grow = rowlist[m0 + srow];
    const float* gA = H + (size_t)grow * DIM + kslice * 1024 + scol;
    const int soff = (srow * 128 + scol * 2) ^ ((srow & 7) << 4);

    const unsigned short* wpb = Wp + (size_t)(wave * 2) * 32768 + lane * 8;

    f32x4 acc[4][2] = {};
    float4 pa0, pb0, pa1, pb1;
    short8 b0[2][2], b1[2][2];

#define LOADA(pa, pb, KT) { \
    pa = *(const float4*)(gA + (KT) * 64); \
    pb = *(const float4*)(gA + (KT) * 64 + 4); }

#define LOADB(B, KT) { \
    _Pragma("unroll") \
    for (int ks = 0; ks < 2; ++ks) \
        _Pragma("unroll") \
        for (int j = 0; j < 2; ++j) \
            B[ks][j] = *(const short8*)(wpb + (size_t)j * 32768 + ((kslice << 5) + (KT) * 2 + ks) * 512); }

#define WRITES(BUFB, pa, pb) { \
    *(short8*)(As + (BUFB) + soff) = cvt8(pa, pb); }

#define COMPUTE(BUFB, B) { \
    short8 a_[2][4]; \
    _Pragma("unroll") \
    for (int ks = 0; ks < 2; ++ks) \
        _Pragma("unroll") \
        for (int i = 0; i < 4; ++i) { \
            int row_ = i * 16 + (lane & 15); \
            int off_ = (row_ * 128 + ks * 64 + ((lane >> 4) << 4)) ^ ((row_ & 7) << 4); \
            a_[ks][i] = *(const short8*)(As + (BUFB) + off_); \
        } \
    __builtin_amdgcn_s_setprio(1); \
    _Pragma("unroll") \
    for (int ks = 0; ks < 2; ++ks) \
        _Pragma("unroll") \
        for (int i = 0; i < 4; ++i) \
            _Pragma("unroll") \
            for (int j = 0; j < 2; ++j) \
                acc[i][j] = __builtin_amdgcn_mfma_f32_16x16x32_bf16(a_[ks][i], B[ks][j], acc[i][j], 0, 0, 0); \
    __builtin_amdgcn_s_setprio(0); }

    // ---- prologue ----
    LOADA(pa0, pb0, 0);
    LOADB(b0, 0);
    WRITES(0, pa0, pb0);
    LOADA(pa1, pb1, 1);
    BARRIER();

    // ---- 16 K-steps (K=1024), unrolled x2, 1 lgkm-barrier per step ----
    for (int it = 0; it < 16; it += 2) {
        if (it + 2 < 16) LOADA(pa0, pb0, it + 2);
        LOADB(b1, it + 1);
        WRITES(8192, pa1, pb1);
        COMPUTE(0, b0);
        BARRIER();

        if (it + 3 < 16) LOADA(pa1, pb1, it + 3);
        if (it + 2 < 16) { LOADB(b0, it + 2); WRITES(0, pa0, pb0); }
        COMPUTE(8192, b1);
        BARRIER();
    }

    // ---- epilogue: C/D layout col=lane&15, row=(lane>>4)*4+r ; bf16 store ----
    #pragma unroll
    for (int i = 0; i < 4; ++i)
        #pragma unroll
        for (int j = 0; j < 2; ++j)
            #pragma unroll
            for (int r = 0; r < 4; ++r) {
                int row = m0 + i * 16 + (lane >> 4) * 4 + r;
                int col = wn + j * 16 + (lane & 15);
                CZout[(size_t)row * NC + col] = f2bf(acc[i][j][r]);
            }
#undef LOADA
#undef LOADB
#undef WRITES
#undef COMPUTE
}

// ---------- Kernel 4: gather (via invmap) + masked softmax + reduce ----------
__global__ __launch_bounds__(256) void finalize(
    const unsigned short* __restrict__ CZp,
    const int*   __restrict__ mask,
    const int*   __restrict__ idx,
    const int*   __restrict__ invmap,
    const float* __restrict__ Bpos,
    float*       __restrict__ out)
{
    const unsigned short* CZ0 = CZp;
    const unsigned short* CZ1 = CZp + HALFCZ;

    int t  = threadIdx.x;
    int lp = t & 63;
    int q  = blockIdx.x * 4 + (t >> 6);
    q = __builtin_amdgcn_readfirstlane(q);
    int b  = q >> 10;
    int ce = lp * 2;

    int rows[8];
    unsigned mbits = 0;
    #pragma unroll
    for (int l = 0; l < 8; ++l) {
        int m   = mask[q * 8 + l];
        int tok = idx[q * 8 + l];
        if (m) {
            rows[l] = invmap[b * 4096 + tok];   // compact row (written this call)
            mbits |= 1u << l;
        } else rows[l] = 0;
    }

    float2 z[8], c[8];
    float2 mx = {-1e30f, -1e30f};
    #pragma unroll
    for (int l = 0; l < 8; ++l) {
        if (mbits & (1u << l)) {
            size_t base = (size_t)rows[l] * NC;
            float2 z0 = ld2bf(CZ0 + base + CDIM + ce);
            float2 z1 = ld2bf(CZ1 + base + CDIM + ce);
            float2 bp = *(const float2*)(Bpos + l * CDIM + ce);
            z[l] = float2{z0.x + z1.x + bp.x, z0.y + z1.y + bp.y};
            float2 c0 = ld2bf(CZ0 + base + ce);
            float2 c1 = ld2bf(CZ1 + base + ce);
            c[l] = float2{c0.x + c1.x, c0.y + c1.y};
            mx.x = fmaxf(mx.x, z[l].x);
            mx.y = fmaxf(mx.y, z[l].y);
        }
    }

    float2 num = {0.f, 0.f}, den = {0.f, 0.f};
    #pragma unroll
    for (int l = 0; l < 8; ++l) {
        if (mbits & (1u << l)) {
            float wx = __expf(z[l].x - mx.x);
            float wy = __expf(z[l].y - mx.y);
            den.x += wx;            den.y += wy;
            num.x += wx * c[l].x;   num.y += wy * c[l].y;
        }
    }
    float2 r = mbits ? float2{num.x / den.x, num.y / den.y} : float2{0.f, 0.f};
    *(float2*)(out + (size_t)q * CDIM + ce) = r;
}

extern "C" void kernel_launch(void* const* d_in, const int* in_sizes, int n_in,
                              void* d_out, int out_size, void* d_ws, size_t ws_size,
                              hipStream_t stream) {
    const float* h    = (const float*)d_in[0];
    const int*   mask = (const int*)d_in[1];
    const int*   idx  = (const int*)d_in[2];
    const float* Wkv  = (const float*)d_in[3];
    const float* Wz   = (const float*)d_in[4];
    const float* Bpos = (const float*)d_in[5];
    float* out = (float*)d_out;

    char* ws = (char*)d_ws;
    unsigned short* Wp      = (unsigned short*)ws;              // 1 MB
    int*            flags   = (int*)(ws + 0x100000);            // 64 KB
    int*            invmap  = (int*)(ws + 0x110000);            // 64 KB
    int*            rowlist = (int*)(ws + 0x120000);            // 64 KB
    int*            nref    = (int*)(ws + 0x130000);            // 4 B
    unsigned short* CZp     = (unsigned short*)(ws + 0x200000); // 2 x 8.4 MB

    hipMemsetAsync(flags, 0, NROWS * sizeof(int), stream);
    convmark<<<384, 256, 0, stream>>>(Wkv, Wz, Wp, mask, idx, flags);
    compact<<<1, 1024, 0, stream>>>(flags, rowlist, invmap, nref);
    gemm_hw<<<384, 512, 0, stream>>>(h, Wp, rowlist, nref, CZp);
    finalize<<<1024, 256, 0, stream>>>(CZp, mask, idx, invmap, Bpos, out);
}

// Round 14
// 51.289 us; speedup vs baseline: 1.0784x; 1.0784x over previous
//
#include <hip/hip_runtime.h>
#include <hip/hip_bf16.h>

// PhraseCompressor: B=4, T=4096, D=2048, P=1024, Lmax=8, c=128
#define DIM   2048
#define NC    256
#define CDIM  128
#define NROWS 16384
#define HALFCZ (16384u * 256u)   // elems per split-K partial

typedef __attribute__((ext_vector_type(8))) short short8;
typedef __attribute__((ext_vector_type(4))) float f32x4;

static __device__ __forceinline__ unsigned short f2bf(float f) {
    union { float f; unsigned u; } v; v.f = f;
    return (unsigned short)((v.u + 0x7fffu + ((v.u >> 16) & 1u)) >> 16);  // RNE
}

static __device__ __forceinline__ short8 cvt8(float4 a, float4 b) {
    union { __hip_bfloat162 h2[4]; short8 s; } u;
    u.h2[0] = __float22bfloat162_rn(float2{a.x, a.y});
    u.h2[1] = __float22bfloat162_rn(float2{a.z, a.w});
    u.h2[2] = __float22bfloat162_rn(float2{b.x, b.y});
    u.h2[3] = __float22bfloat162_rn(float2{b.z, b.w});
    return u.s;
}

static __device__ __forceinline__ float2 ld2bf(const unsigned short* p) {
    unsigned v = *(const unsigned*)p;
    union { unsigned u; float f; } lo, hi;
    lo.u = v << 16;
    hi.u = v & 0xffff0000u;
    return float2{lo.f, hi.f};
}

#define BARRIER() { asm volatile("s_waitcnt lgkmcnt(0)" ::: "memory"); \
                    __builtin_amdgcn_s_barrier(); }

// ---------- Kernel 1 (fused): convert W (blocks 0..255) + mark+assign (256..383)
// Mark phase: first masked slot to touch a row claims it via atomicCAS and
// assigns the next compact index via atomicAdd. No separate scan kernel.
// Compact ORDER is nondeterministic; output is order-invariant (finalize
// reads through invmap, each row's projection identical at any slot).
__global__ __launch_bounds__(256) void convmark(const float* __restrict__ Wkv,
                                                const float* __restrict__ Wz,
                                                unsigned short* __restrict__ Wp,
                                                const int* __restrict__ mask,
                                                const int* __restrict__ idx,
                                                int* __restrict__ invmap,
                                                int* __restrict__ rowlist,
                                                int* __restrict__ nref) {
    int bid = blockIdx.x;
    if (bid < 256) {
        int tid = bid * 256 + threadIdx.x;
        int l = tid & 63;
        int s = (tid >> 6) & 63;
        int f = tid >> 12;
        int n = f * 16 + (l & 15);
        int k = s * 32 + ((l >> 4) << 3);
        const float* src = (n < CDIM) ? (Wkv + (size_t)n * DIM + k)
                                      : (Wz + (size_t)(n - CDIM) * DIM + k);
        float4 f0 = *(const float4*)src;
        float4 f1 = *(const float4*)(src + 4);
        *(short8*)(Wp + (size_t)tid * 8) = cvt8(f0, f1);
    } else {
        int s = (bid - 256) * 256 + threadIdx.x;   // 0..32767 slots (8192/batch)
        if (mask[s]) {
            int row = (s >> 13) * 4096 + idx[s];   // b*T + tok
            if (atomicCAS(&invmap[row], -1, -2) == -1) {
                int c = atomicAdd(nref, 1);
                rowlist[c] = row;
                invmap[row] = c;
            }
        }
    }
}

// ---------- Kernel 2: CZp[ks][compact][256] = h[rowlist] @ W^T ----------
// EXACT r11 inner loop (best known, 41.99us): BM=64, BN=256, split-K=2,
// 512 thr = 8 full-M waves (64 rows x 32 cols each) -> acc[4][2].
// Grid 512, early-exit when m0 >= count; indirect rows via rowlist (guarded).
__global__ __launch_bounds__(512, 4) void gemm_hw(
    const float* __restrict__ H,
    const unsigned short* __restrict__ Wp,
    const int* __restrict__ rowlist,
    const int* __restrict__ nref,
    unsigned short* __restrict__ CZp)
{
    __shared__ unsigned char As[2 * 64 * 128];

    const int bid    = blockIdx.x;
    const int kslice = bid & 1;
    const int m0     = (bid >> 1) * 64;
    const int count  = nref[0];
    if (m0 >= count) return;            // tile fully padding -> skip

    const int tid    = threadIdx.x;
    const int lane   = tid & 63;
    const int wave   = tid >> 6;        // 0..7
    const int wn     = wave * 32;

    unsigned short* CZout = CZp + (size_t)kslice * HALFCZ;

    // A staging: thread -> 8 consecutive floats of its (indirect) row
    const int srow = tid >> 3;           // 0..63
    const int scol = (tid & 7) * 8;      // 0..56
    const int rl   = m0 + srow;
    const int grow = (rl < count) ? rowlist[rl] : 0;   // guard poisoned pad
    const float* gA = H + (size_t)grow * DIM + kslice * 1024 + scol;
    const int soff = (srow * 128 + scol * 2) ^ ((srow & 7) << 4);

    const unsigned short* wpb = Wp + (size_t)(wave * 2) * 32768 + lane * 8;

    f32x4 acc[4][2] = {};
    float4 pa0, pb0, pa1, pb1;
    short8 b0[2][2], b1[2][2];

#define LOADA(pa, pb, KT) { \
    pa = *(const float4*)(gA + (KT) * 64); \
    pb = *(const float4*)(gA + (KT) * 64 + 4); }

#define LOADB(B, KT) { \
    _Pragma("unroll") \
    for (int ks = 0; ks < 2; ++ks) \
        _Pragma("unroll") \
        for (int j = 0; j < 2; ++j) \
            B[ks][j] = *(const short8*)(wpb + (size_t)j * 32768 + ((kslice << 5) + (KT) * 2 + ks) * 512); }

#define WRITES(BUFB, pa, pb) { \
    *(short8*)(As + (BUFB) + soff) = cvt8(pa, pb); }

#define COMPUTE(BUFB, B) { \
    short8 a_[2][4]; \
    _Pragma("unroll") \
    for (int ks = 0; ks < 2; ++ks) \
        _Pragma("unroll") \
        for (int i = 0; i < 4; ++i) { \
            int row_ = i * 16 + (lane & 15); \
            int off_ = (row_ * 128 + ks * 64 + ((lane >> 4) << 4)) ^ ((row_ & 7) << 4); \
            a_[ks][i] = *(const short8*)(As + (BUFB) + off_); \
        } \
    __builtin_amdgcn_s_setprio(1); \
    _Pragma("unroll") \
    for (int ks = 0; ks < 2; ++ks) \
        _Pragma("unroll") \
        for (int i = 0; i < 4; ++i) \
            _Pragma("unroll") \
            for (int j = 0; j < 2; ++j) \
                acc[i][j] = __builtin_amdgcn_mfma_f32_16x16x32_bf16(a_[ks][i], B[ks][j], acc[i][j], 0, 0, 0); \
    __builtin_amdgcn_s_setprio(0); }

    // ---- prologue: stage step0, prefetch step1 ----
    LOADA(pa0, pb0, 0);
    LOADB(b0, 0);
    WRITES(0, pa0, pb0);
    LOADA(pa1, pb1, 1);
    BARRIER();

    // ---- 16 K-steps (K=1024), unrolled x2, 1 lgkm-barrier per step ----
    for (int it = 0; it < 16; it += 2) {
        if (it + 2 < 16) LOADA(pa0, pb0, it + 2);
        LOADB(b1, it + 1);
        WRITES(8192, pa1, pb1);                 // stage it+1 into buf1
        COMPUTE(0, b0);
        BARRIER();

        if (it + 3 < 16) LOADA(pa1, pb1, it + 3);
        if (it + 2 < 16) { LOADB(b0, it + 2); WRITES(0, pa0, pb0); }
        COMPUTE(8192, b1);
        BARRIER();
    }

    // ---- epilogue: C/D layout col=lane&15, row=(lane>>4)*4+r ; bf16 store ----
    #pragma unroll
    for (int i = 0; i < 4; ++i)
        #pragma unroll
        for (int j = 0; j < 2; ++j)
            #pragma unroll
            for (int r = 0; r < 4; ++r) {
                int row = m0 + i * 16 + (lane >> 4) * 4 + r;
                int col = wn + j * 16 + (lane & 15);
                CZout[(size_t)row * NC + col] = f2bf(acc[i][j][r]);
            }
#undef LOADA
#undef LOADB
#undef WRITES
#undef COMPUTE
}

// ---------- Kernel 3: gather (via invmap) + masked softmax + reduce ----------
__global__ __launch_bounds__(256) void finalize(
    const unsigned short* __restrict__ CZp,
    const int*   __restrict__ mask,
    const int*   __restrict__ idx,
    const int*   __restrict__ invmap,
    const float* __restrict__ Bpos,
    float*       __restrict__ out)
{
    const unsigned short* CZ0 = CZp;
    const unsigned short* CZ1 = CZp + HALFCZ;

    int t  = threadIdx.x;
    int lp = t & 63;
    int q  = blockIdx.x * 4 + (t >> 6);
    q = __builtin_amdgcn_readfirstlane(q);
    int b  = q >> 10;
    int ce = lp * 2;

    int rows[8];
    unsigned mbits = 0;
    #pragma unroll
    for (int l = 0; l < 8; ++l) {
        int m   = mask[q * 8 + l];
        int tok = idx[q * 8 + l];
        if (m) {
            rows[l] = invmap[b * 4096 + tok];   // set this call (masked => marked)
            mbits |= 1u << l;
        } else rows[l] = 0;
    }

    float2 z[8], c[8];
    float2 mx = {-1e30f, -1e30f};
    #pragma unroll
    for (int l = 0; l < 8; ++l) {
        if (mbits & (1u << l)) {
            size_t base = (size_t)rows[l] * NC;
            float2 z0 = ld2bf(CZ0 + base + CDIM + ce);
            float2 z1 = ld2bf(CZ1 + base + CDIM + ce);
            float2 bp = *(const float2*)(Bpos + l * CDIM + ce);
            z[l] = float2{z0.x + z1.x + bp.x, z0.y + z1.y + bp.y};
            float2 c0 = ld2bf(CZ0 + base + ce);
            float2 c1 = ld2bf(CZ1 + base + ce);
            c[l] = float2{c0.x + c1.x, c0.y + c1.y};
            mx.x = fmaxf(mx.x, z[l].x);
            mx.y = fmaxf(mx.y, z[l].y);
        }
    }

    float2 num = {0.f, 0.f}, den = {0.f, 0.f};
    #pragma unroll
    for (int l = 0; l < 8; ++l) {
        if (mbits & (1u << l)) {
            float wx = __expf(z[l].x - mx.x);
            float wy = __expf(z[l].y - mx.y);
            den.x += wx;            den.y += wy;
            num.x += wx * c[l].x;   num.y += wy * c[l].y;
        }
    }
    float2 r = mbits ? float2{num.x / den.x, num.y / den.y} : float2{0.f, 0.f};
    *(float2*)(out + (size_t)q * CDIM + ce) = r;
}

extern "C" void kernel_launch(void* const* d_in, const int* in_sizes, int n_in,
                              void* d_out, int out_size, void* d_ws, size_t ws_size,
                              hipStream_t stream) {
    const float* h    = (const float*)d_in[0];
    const int*   mask = (const int*)d_in[1];
    const int*   idx  = (const int*)d_in[2];
    const float* Wkv  = (const float*)d_in[3];
    const float* Wz   = (const float*)d_in[4];
    const float* Bpos = (const float*)d_in[5];
    float* out = (float*)d_out;

    char* ws = (char*)d_ws;
    unsigned short* Wp      = (unsigned short*)ws;              // 1 MB
    int*            invmap  = (int*)(ws + 0x110000);            // 64 KB
    int*            rowlist = (int*)(ws + 0x120000);            // 64 KB
    int*            nref    = (int*)(ws + 0x130000);            // 4 B
    unsigned short* CZp     = (unsigned short*)(ws + 0x200000); // 2 x 8.4 MB

    hipMemsetAsync(invmap, 0xFF, NROWS * sizeof(int), stream);  // -1 = unclaimed
    hipMemsetAsync(nref, 0, sizeof(int), stream);
    convmark<<<384, 256, 0, stream>>>(Wkv, Wz, Wp, mask, idx, invmap, rowlist, nref);
    gemm_hw<<<512, 512, 0, stream>>>(h, Wp, rowlist, nref, CZp);
    finalize<<<1024, 256, 0, stream>>>(CZp, mask, idx, invmap, Bpos, out);
}

// Round 16
// 42.048 us; speedup vs baseline: 1.3154x; 1.2198x over previous
//
#include <hip/hip_runtime.h>
#include <hip/hip_bf16.h>

// PhraseCompressor: B=4, T=4096, D=2048, P=1024, Lmax=8, c=128
#define DIM   2048
#define NC    256
#define CDIM  128
#define HALFCZ (16384u * 256u)   // elems per split-K partial

typedef __attribute__((ext_vector_type(8))) short short8;
typedef __attribute__((ext_vector_type(4))) float f32x4;

static __device__ __forceinline__ unsigned short f2bf(float f) {
    union { float f; unsigned u; } v; v.f = f;
    return (unsigned short)((v.u + 0x7fffu + ((v.u >> 16) & 1u)) >> 16);  // RNE
}

// pack 8 f32 -> 8 bf16 (compiler emits v_cvt_pk_bf16_f32 pairs)
static __device__ __forceinline__ short8 cvt8(float4 a, float4 b) {
    union { __hip_bfloat162 h2[4]; short8 s; } u;
    u.h2[0] = __float22bfloat162_rn(float2{a.x, a.y});
    u.h2[1] = __float22bfloat162_rn(float2{a.z, a.w});
    u.h2[2] = __float22bfloat162_rn(float2{b.x, b.y});
    u.h2[3] = __float22bfloat162_rn(float2{b.z, b.w});
    return u.s;
}

// two adjacent bf16 -> float2 (lo = v<<16, hi = v & 0xffff0000)
static __device__ __forceinline__ float2 ld2bf(const unsigned short* p) {
    unsigned v = *(const unsigned*)p;
    union { unsigned u; float f; } lo, hi;
    lo.u = v << 16;
    hi.u = v & 0xffff0000u;
    return float2{lo.f, hi.f};
}

// lgkm-only barrier: keep global (vmcnt) prefetch loads in flight across it.
#define BARRIER() { asm volatile("s_waitcnt lgkmcnt(0)" ::: "memory"); \
                    __builtin_amdgcn_s_barrier(); }

// ---------- Kernel 1: pack W_kv|W_z into fragment-major bf16 Wp ----------
// frag f 0..15 (cols f*16..), k-subtile s 0..63 (k = s*32..)
// Wp[((f*64+s)*64+l)*8+e] = W[f*16+(l&15)][s*32+(l>>4)*8+e]
__global__ __launch_bounds__(256) void convert_w(const float* __restrict__ Wkv,
                                                 const float* __restrict__ Wz,
                                                 unsigned short* __restrict__ Wp) {
    int tid = blockIdx.x * 256 + threadIdx.x;      // 65536 threads
    int l = tid & 63;
    int s = (tid >> 6) & 63;
    int f = tid >> 12;
    int n = f * 16 + (l & 15);
    int k = s * 32 + ((l >> 4) << 3);
    const float* src = (n < CDIM) ? (Wkv + (size_t)n * DIM + k)
                                  : (Wz + (size_t)(n - CDIM) * DIM + k);
    float4 f0 = *(const float4*)src;
    float4 f1 = *(const float4*)(src + 4);
    *(short8*)(Wp + (size_t)tid * 8) = cvt8(f0, f1);
}

// ---------- Kernel 2: CZp[ks][16384][256] = h @ W^T (K-slice, bf16 out) ------
// BM=64, BN=256, split-K=2. 512 thr = 8 waves; wave w: 64 rows x cols w*32..+31
// -> acc[4][2]. Grid 512 -> 2 blocks/CU = 16 waves/CU = 4 waves/SIMD.
// A: 64x64 bf16 LDS dbuf (16 KB), XOR swizzle, reg-staged depth-2.
// B: fragment-major Wp (L2), unique frags per wave, reg-prefetched depth-1.
// lgkm-only barriers (T4); setprio around MFMA cluster (T5).
__global__ __launch_bounds__(512, 4) void gemm_hw(
    const float* __restrict__ H,
    const unsigned short* __restrict__ Wp,
    unsigned short* __restrict__ CZp)
{
    __shared__ unsigned char As[2 * 64 * 128];

    const int tid    = threadIdx.x;
    const int lane   = tid & 63;
    const int wave   = tid >> 6;        // 0..7
    const int wn     = wave * 32;
    const int bid    = blockIdx.x;
    const int kslice = bid & 1;
    const int m0     = (bid >> 1) * 64;

    unsigned short* CZout = CZp + (size_t)kslice * HALFCZ;

    // A staging: thread -> 8 consecutive floats of one row (one short8 write)
    const int srow = tid >> 3;           // 0..63
    const int scol = (tid & 7) * 8;      // 0..56
    const float* gA = H + (size_t)(m0 + srow) * DIM + kslice * 1024 + scol;
    const int soff = (srow * 128 + scol * 2) ^ ((srow & 7) << 4);

    // B fragment base: frag index = wave*2 + j ; addr = wpb + j*32768 + s*512
    const unsigned short* wpb = Wp + (size_t)(wave * 2) * 32768 + lane * 8;

    f32x4 acc[4][2] = {};
    float4 pa0, pb0, pa1, pb1;
    short8 b0[2][2], b1[2][2];

#define LOADA(pa, pb, KT) { \
    pa = *(const float4*)(gA + (KT) * 64); \
    pb = *(const float4*)(gA + (KT) * 64 + 4); }

#define LOADB(B, KT) { \
    _Pragma("unroll") \
    for (int ks = 0; ks < 2; ++ks) \
        _Pragma("unroll") \
        for (int j = 0; j < 2; ++j) \
            B[ks][j] = *(const short8*)(wpb + (size_t)j * 32768 + ((kslice << 5) + (KT) * 2 + ks) * 512); }

#define WRITES(BUFB, pa, pb) { \
    *(short8*)(As + (BUFB) + soff) = cvt8(pa, pb); }

#define COMPUTE(BUFB, B) { \
    short8 a_[2][4]; \
    _Pragma("unroll") \
    for (int ks = 0; ks < 2; ++ks) \
        _Pragma("unroll") \
        for (int i = 0; i < 4; ++i) { \
            int row_ = i * 16 + (lane & 15); \
            int off_ = (row_ * 128 + ks * 64 + ((lane >> 4) << 4)) ^ ((row_ & 7) << 4); \
            a_[ks][i] = *(const short8*)(As + (BUFB) + off_); \
        } \
    __builtin_amdgcn_s_setprio(1); \
    _Pragma("unroll") \
    for (int ks = 0; ks < 2; ++ks) \
        _Pragma("unroll") \
        for (int i = 0; i < 4; ++i) \
            _Pragma("unroll") \
            for (int j = 0; j < 2; ++j) \
                acc[i][j] = __builtin_amdgcn_mfma_f32_16x16x32_bf16(a_[ks][i], B[ks][j], acc[i][j], 0, 0, 0); \
    __builtin_amdgcn_s_setprio(0); }

    // ---- prologue: stage step0, prefetch step1 ----
    LOADA(pa0, pb0, 0);
    LOADB(b0, 0);
    WRITES(0, pa0, pb0);
    LOADA(pa1, pb1, 1);
    BARRIER();

    // ---- 16 K-steps (K=1024), unrolled x2, 1 lgkm-barrier per step ----
    // HBM loads (LOADA) issued first in each half-step: longest latency first.
    for (int it = 0; it < 16; it += 2) {
        if (it + 2 < 16) LOADA(pa0, pb0, it + 2);
        LOADB(b1, it + 1);
        WRITES(8192, pa1, pb1);                 // stage it+1 into buf1
        COMPUTE(0, b0);
        BARRIER();

        if (it + 3 < 16) LOADA(pa1, pb1, it + 3);
        if (it + 2 < 16) { LOADB(b0, it + 2); WRITES(0, pa0, pb0); }
        COMPUTE(8192, b1);
        BARRIER();
    }

    // ---- epilogue: C/D layout col=lane&15, row=(lane>>4)*4+r ; bf16 store ----
    #pragma unroll
    for (int i = 0; i < 4; ++i)
        #pragma unroll
        for (int j = 0; j < 2; ++j)
            #pragma unroll
            for (int r = 0; r < 4; ++r) {
                int row = m0 + i * 16 + (lane >> 4) * 4 + r;
                int col = wn + j * 16 + (lane & 15);
                CZout[(size_t)row * NC + col] = f2bf(acc[i][j][r]);
            }
#undef LOADA
#undef LOADB
#undef WRITES
#undef COMPUTE
}

// ---------- Kernel 3: sum split-K + gather + masked softmax + reduce ----------
// 64 threads per phrase, 2 channels per thread (u32 bf16-pair gathers).
__global__ __launch_bounds__(256) void finalize(
    const unsigned short* __restrict__ CZp,
    const int*   __restrict__ mask,
    const int*   __restrict__ idx,
    const float* __restrict__ Bpos,
    float*       __restrict__ out)
{
    const unsigned short* CZ0 = CZp;
    const unsigned short* CZ1 = CZp + HALFCZ;

    int t  = threadIdx.x;
    int lp = t & 63;                       // channel-pair index 0..63
    int q  = blockIdx.x * 4 + (t >> 6);    // linear phrase 0..4095
    q = __builtin_amdgcn_readfirstlane(q); // wave-uniform -> scalar loads below
    int b  = q >> 10;
    int ce = lp * 2;                       // even channel

    int rows[8];
    unsigned mbits = 0;
    #pragma unroll
    for (int l = 0; l < 8; ++l) {
        int m   = mask[q * 8 + l];
        int tok = idx[q * 8 + l];
        rows[l] = b * 4096 + tok;
        if (m) mbits |= 1u << l;
    }

    float2 z[8], c[8];
    float2 mx = {-1e30f, -1e30f};
    #pragma unroll
    for (int l = 0; l < 8; ++l) {
        if (mbits & (1u << l)) {
            size_t base = (size_t)rows[l] * NC;
            float2 z0 = ld2bf(CZ0 + base + CDIM + ce);
            float2 z1 = ld2bf(CZ1 + base + CDIM + ce);
            float2 bp = *(const float2*)(Bpos + l * CDIM + ce);
            z[l] = float2{z0.x + z1.x + bp.x, z0.y + z1.y + bp.y};
            float2 c0 = ld2bf(CZ0 + base + ce);
            float2 c1 = ld2bf(CZ1 + base + ce);
            c[l] = float2{c0.x + c1.x, c0.y + c1.y};
            mx.x = fmaxf(mx.x, z[l].x);
            mx.y = fmaxf(mx.y, z[l].y);
        }
    }

    float2 num = {0.f, 0.f}, den = {0.f, 0.f};
    #pragma unroll
    for (int l = 0; l < 8; ++l) {
        if (mbits & (1u << l)) {
            float wx = __expf(z[l].x - mx.x);
            float wy = __expf(z[l].y - mx.y);
            den.x += wx;            den.y += wy;
            num.x += wx * c[l].x;   num.y += wy * c[l].y;
        }
    }
    float2 r = mbits ? float2{num.x / den.x, num.y / den.y} : float2{0.f, 0.f};
    *(float2*)(out + (size_t)q * CDIM + ce) = r;
}

extern "C" void kernel_launch(void* const* d_in, const int* in_sizes, int n_in,
                              void* d_out, int out_size, void* d_ws, size_t ws_size,
                              hipStream_t stream) {
    const float* h    = (const float*)d_in[0];
    const int*   mask = (const int*)d_in[1];
    const int*   idx  = (const int*)d_in[2];
    const float* Wkv  = (const float*)d_in[3];
    const float* Wz   = (const float*)d_in[4];
    const float* Bpos = (const float*)d_in[5];
    float* out = (float*)d_out;

    unsigned short* Wp  = (unsigned short*)d_ws;                    // 1 MB packed W
    unsigned short* CZp = (unsigned short*)((char*)d_ws + 2 * 1024 * 1024); // 2x8.4 MB bf16

    convert_w<<<256, 256, 0, stream>>>(Wkv, Wz, Wp);
    gemm_hw<<<512, 512, 0, stream>>>(h, Wp, CZp);
    finalize<<<1024, 256, 0, stream>>>(CZp, mask, idx, Bpos, out);
}

// Round 18
// 42.010 us; speedup vs baseline: 1.3165x; 1.0009x over previous
//
#include <hip/hip_runtime.h>
#include <hip/hip_bf16.h>

// PhraseCompressor: B=4, T=4096, D=2048, P=1024, Lmax=8, c=128
#define DIM   2048
#define NC    256
#define CDIM  128
#define HALFCZ (16384u * 256u)   // elems per split-K partial

typedef __attribute__((ext_vector_type(8))) short short8;
typedef __attribute__((ext_vector_type(4))) float f32x4;

static __device__ __forceinline__ unsigned short f2bf(float f) {
    union { float f; unsigned u; } v; v.f = f;
    return (unsigned short)((v.u + 0x7fffu + ((v.u >> 16) & 1u)) >> 16);  // RNE
}

// pack 8 f32 -> 8 bf16 (compiler emits v_cvt_pk_bf16_f32 pairs)
static __device__ __forceinline__ short8 cvt8(float4 a, float4 b) {
    union { __hip_bfloat162 h2[4]; short8 s; } u;
    u.h2[0] = __float22bfloat162_rn(float2{a.x, a.y});
    u.h2[1] = __float22bfloat162_rn(float2{a.z, a.w});
    u.h2[2] = __float22bfloat162_rn(float2{b.x, b.y});
    u.h2[3] = __float22bfloat162_rn(float2{b.z, b.w});
    return u.s;
}

// two adjacent bf16 -> float2 (lo = v<<16, hi = v & 0xffff0000)
static __device__ __forceinline__ float2 ld2bf(const unsigned short* p) {
    unsigned v = *(const unsigned*)p;
    union { unsigned u; float f; } lo, hi;
    lo.u = v << 16;
    hi.u = v & 0xffff0000u;
    return float2{lo.f, hi.f};
}

// lgkm-only barrier: keep global (vmcnt) prefetch loads in flight across it.
#define BARRIER() { asm volatile("s_waitcnt lgkmcnt(0)" ::: "memory"); \
                    __builtin_amdgcn_s_barrier(); }

// ---------- Kernel 1: pack W_kv|W_z into fragment-major bf16 Wp ----------
// frag f 0..15 (cols f*16..), k-subtile s 0..63 (k = s*32..)
// Wp[((f*64+s)*64+l)*8+e] = W[f*16+(l&15)][s*32+(l>>4)*8+e]
__global__ __launch_bounds__(256) void convert_w(const float* __restrict__ Wkv,
                                                 const float* __restrict__ Wz,
                                                 unsigned short* __restrict__ Wp) {
    int tid = blockIdx.x * 256 + threadIdx.x;      // 65536 threads
    int l = tid & 63;
    int s = (tid >> 6) & 63;
    int f = tid >> 12;
    int n = f * 16 + (l & 15);
    int k = s * 32 + ((l >> 4) << 3);
    const float* src = (n < CDIM) ? (Wkv + (size_t)n * DIM + k)
                                  : (Wz + (size_t)(n - CDIM) * DIM + k);
    float4 f0 = *(const float4*)src;
    float4 f1 = *(const float4*)(src + 4);
    *(short8*)(Wp + (size_t)tid * 8) = cvt8(f0, f1);
}

// ---------- Kernel 2: CZp[ks][16384][256] = h @ W^T (K-slice, bf16 out) ------
// BM=64, BN=256, split-K=2. 512 thr = 8 waves; wave w: 64 rows x cols w*32..+31
// -> acc[4][2]. Grid 512 -> 2 blocks/CU = 16 waves/CU = 4 waves/SIMD.
// A: 64x64 bf16 LDS dbuf (16 KB), XOR swizzle, reg-staged depth-2.
// B: fragment-major Wp (L2), unique frags per wave, reg-prefetched depth-1.
// lgkm-only barriers (T4); setprio around MFMA cluster (T5).
__global__ __launch_bounds__(512, 4) void gemm_hw(
    const float* __restrict__ H,
    const unsigned short* __restrict__ Wp,
    unsigned short* __restrict__ CZp)
{
    __shared__ unsigned char As[2 * 64 * 128];

    const int tid    = threadIdx.x;
    const int lane   = tid & 63;
    const int wave   = tid >> 6;        // 0..7
    const int wn     = wave * 32;
    const int bid    = blockIdx.x;
    const int kslice = bid & 1;
    const int m0     = (bid >> 1) * 64;

    unsigned short* CZout = CZp + (size_t)kslice * HALFCZ;

    // A staging: thread -> 8 consecutive floats of one row (one short8 write)
    const int srow = tid >> 3;           // 0..63
    const int scol = (tid & 7) * 8;      // 0..56
    const float* gA = H + (size_t)(m0 + srow) * DIM + kslice * 1024 + scol;
    const int soff = (srow * 128 + scol * 2) ^ ((srow & 7) << 4);

    // B fragment base: frag index = wave*2 + j ; addr = wpb + j*32768 + s*512
    const unsigned short* wpb = Wp + (size_t)(wave * 2) * 32768 + lane * 8;

    f32x4 acc[4][2] = {};
    float4 pa0, pb0, pa1, pb1;
    short8 b0[2][2], b1[2][2];

#define LOADA(pa, pb, KT) { \
    pa = *(const float4*)(gA + (KT) * 64); \
    pb = *(const float4*)(gA + (KT) * 64 + 4); }

#define LOADB(B, KT) { \
    _Pragma("unroll") \
    for (int ks = 0; ks < 2; ++ks) \
        _Pragma("unroll") \
        for (int j = 0; j < 2; ++j) \
            B[ks][j] = *(const short8*)(wpb + (size_t)j * 32768 + ((kslice << 5) + (KT) * 2 + ks) * 512); }

#define WRITES(BUFB, pa, pb) { \
    *(short8*)(As + (BUFB) + soff) = cvt8(pa, pb); }

#define COMPUTE(BUFB, B) { \
    short8 a_[2][4]; \
    _Pragma("unroll") \
    for (int ks = 0; ks < 2; ++ks) \
        _Pragma("unroll") \
        for (int i = 0; i < 4; ++i) { \
            int row_ = i * 16 + (lane & 15); \
            int off_ = (row_ * 128 + ks * 64 + ((lane >> 4) << 4)) ^ ((row_ & 7) << 4); \
            a_[ks][i] = *(const short8*)(As + (BUFB) + off_); \
        } \
    __builtin_amdgcn_s_setprio(1); \
    _Pragma("unroll") \
    for (int ks = 0; ks < 2; ++ks) \
        _Pragma("unroll") \
        for (int i = 0; i < 4; ++i) \
            _Pragma("unroll") \
            for (int j = 0; j < 2; ++j) \
                acc[i][j] = __builtin_amdgcn_mfma_f32_16x16x32_bf16(a_[ks][i], B[ks][j], acc[i][j], 0, 0, 0); \
    __builtin_amdgcn_s_setprio(0); }

    // ---- prologue: stage step0, prefetch step1 ----
    LOADA(pa0, pb0, 0);
    LOADB(b0, 0);
    WRITES(0, pa0, pb0);
    LOADA(pa1, pb1, 1);
    BARRIER();

    // ---- 16 K-steps (K=1024), unrolled x2, 1 lgkm-barrier per step ----
    // HBM loads (LOADA) issued first in each half-step: longest latency first.
    for (int it = 0; it < 16; it += 2) {
        if (it + 2 < 16) LOADA(pa0, pb0, it + 2);
        LOADB(b1, it + 1);
        WRITES(8192, pa1, pb1);                 // stage it+1 into buf1
        COMPUTE(0, b0);
        BARRIER();

        if (it + 3 < 16) LOADA(pa1, pb1, it + 3);
        if (it + 2 < 16) { LOADB(b0, it + 2); WRITES(0, pa0, pb0); }
        COMPUTE(8192, b1);
        BARRIER();
    }

    // ---- epilogue: C/D layout col=lane&15, row=(lane>>4)*4+r ; bf16 store ----
    #pragma unroll
    for (int i = 0; i < 4; ++i)
        #pragma unroll
        for (int j = 0; j < 2; ++j)
            #pragma unroll
            for (int r = 0; r < 4; ++r) {
                int row = m0 + i * 16 + (lane >> 4) * 4 + r;
                int col = wn + j * 16 + (lane & 15);
                CZout[(size_t)row * NC + col] = f2bf(acc[i][j][r]);
            }
#undef LOADA
#undef LOADB
#undef WRITES
#undef COMPUTE
}

// ---------- Kernel 3: sum split-K + gather + masked softmax + reduce ----------
// 64 threads per phrase, 2 channels per thread (u32 bf16-pair gathers).
__global__ __launch_bounds__(256) void finalize(
    const unsigned short* __restrict__ CZp,
    const int*   __restrict__ mask,
    const int*   __restrict__ idx,
    const float* __restrict__ Bpos,
    float*       __restrict__ out)
{
    const unsigned short* CZ0 = CZp;
    const unsigned short* CZ1 = CZp + HALFCZ;

    int t  = threadIdx.x;
    int lp = t & 63;                       // channel-pair index 0..63
    int q  = blockIdx.x * 4 + (t >> 6);    // linear phrase 0..4095
    q = __builtin_amdgcn_readfirstlane(q); // wave-uniform -> scalar loads below
    int b  = q >> 10;
    int ce = lp * 2;                       // even channel

    int rows[8];
    unsigned mbits = 0;
    #pragma unroll
    for (int l = 0; l < 8; ++l) {
        int m   = mask[q * 8 + l];
        int tok = idx[q * 8 + l];
        rows[l] = b * 4096 + tok;
        if (m) mbits |= 1u << l;
    }

    float2 z[8], c[8];
    float2 mx = {-1e30f, -1e30f};
    #pragma unroll
    for (int l = 0; l < 8; ++l) {
        if (mbits & (1u << l)) {
            size_t base = (size_t)rows[l] * NC;
            float2 z0 = ld2bf(CZ0 + base + CDIM + ce);
            float2 z1 = ld2bf(CZ1 + base + CDIM + ce);
            float2 bp = *(const float2*)(Bpos + l * CDIM + ce);
            z[l] = float2{z0.x + z1.x + bp.x, z0.y + z1.y + bp.y};
            float2 c0 = ld2bf(CZ0 + base + ce);
            float2 c1 = ld2bf(CZ1 + base + ce);
            c[l] = float2{c0.x + c1.x, c0.y + c1.y};
            mx.x = fmaxf(mx.x, z[l].x);
            mx.y = fmaxf(mx.y, z[l].y);
        }
    }

    float2 num = {0.f, 0.f}, den = {0.f, 0.f};
    #pragma unroll
    for (int l = 0; l < 8; ++l) {
        if (mbits & (1u << l)) {
            float wx = __expf(z[l].x - mx.x);
            float wy = __expf(z[l].y - mx.y);
            den.x += wx;            den.y += wy;
            num.x += wx * c[l].x;   num.y += wy * c[l].y;
        }
    }
    float2 r = mbits ? float2{num.x / den.x, num.y / den.y} : float2{0.f, 0.f};
    *(float2*)(out + (size_t)q * CDIM + ce) = r;
}

extern "C" void kernel_launch(void* const* d_in, const int* in_sizes, int n_in,
                              void* d_out, int out_size, void* d_ws, size_t ws_size,
                              hipStream_t stream) {
    const float* h    = (const float*)d_in[0];
    const int*   mask = (const int*)d_in[1];
    const int*   idx  = (const int*)d_in[2];
    const float* Wkv  = (const float*)d_in[3];
    const float* Wz   = (const float*)d_in[4];
    const float* Bpos = (const float*)d_in[5];
    float* out = (float*)d_out;

    unsigned short* Wp  = (unsigned short*)d_ws;                    // 1 MB packed W
    unsigned short* CZp = (unsigned short*)((char*)d_ws + 2 * 1024 * 1024); // 2x8.4 MB bf16

    convert_w<<<256, 256, 0, stream>>>(Wkv, Wz, Wp);
    gemm_hw<<<512, 512, 0, stream>>>(h, Wp, CZp);
    finalize<<<1024, 256, 0, stream>>>(CZp, mask, idx, Bpos, out);
}